// Round 8
// baseline (241.651 us; speedup 1.0000x reference)
//
#include <hip/hip_runtime.h>

#define B_N   32768
#define D_RGBc 512
#define D_SPDc 128
#define D_INc  640
#define Hc     256
#define Cc     7

typedef __bf16 bf16x8 __attribute__((ext_vector_type(8)));
typedef float  f32x4  __attribute__((ext_vector_type(4)));
typedef float  f32x16 __attribute__((ext_vector_type(16)));
typedef unsigned int u32;

__device__ __forceinline__ float sigmoidf_(float x) { return 1.0f / (1.0f + __expf(-x)); }
__device__ __forceinline__ float tanhf_(float x)    { float e = __expf(2.f * x); return (e - 1.f) / (e + 1.f); }
__device__ __forceinline__ u32 sw16(int row, int colbyte) { return (u32)(colbyte ^ ((row & 15) << 4)); }

// ---------------- pack weights into MFMA B-fragment order (+ zero counters) ----------------
// frag f = (ntile*(K/16) + kf)*64 + lane, 16B each.
// frag(lane) = W[k0 + kf*16 + (lane>>5)*8 + j][ntile*32 + (lane&31)], j=0..7
__global__ void pack_kernel(const float* __restrict__ W1, const float* __restrict__ W2,
                            const float* __restrict__ W3, const float* __restrict__ sW2,
                            const float* __restrict__ sW3,
                            __bf16* __restrict__ p1, __bf16* __restrict__ p2,
                            __bf16* __restrict__ p3, __bf16* __restrict__ ps2,
                            __bf16* __restrict__ ps3, int* __restrict__ cnt)
{
    if (blockIdx.x == 0 && threadIdx.x < 16) cnt[threadIdx.x] = 0;
    int bid = blockIdx.x;
    const float* src; __bf16* dst; int K, N, nt, kc;
    if (bid < 560)      { int c = bid / 80, r = bid % 80; nt = r / 10; kc = r % 10;
        src = W1 + (size_t)c * D_INc * Hc; dst = p1 + (size_t)c * Hc * D_INc; K = D_INc; N = Hc; }
    else if (bid < 784) { int b = bid - 560; int c = b / 32, r = b % 32; nt = r / 4; kc = r % 4;
        src = W2 + (size_t)c * Hc * Hc; dst = p2 + (size_t)c * Hc * Hc; K = Hc; N = Hc; }
    else if (bid < 1008){ int b = bid - 784; int c = b / 32, r = b % 32; nt = r / 4; kc = r % 4;
        src = W3 + (size_t)c * Hc * Hc; dst = p3 + (size_t)c * Hc * Hc; K = Hc; N = Hc; }
    else if (bid < 1016){ int r = bid - 1008; nt = r / 2; kc = r % 2; src = sW2; dst = ps2; K = D_SPDc; N = D_SPDc; }
    else                { int r = bid - 1016; nt = r / 2; kc = r % 2; src = sW3; dst = ps3; K = D_SPDc; N = D_SPDc; }
    int k0 = kc * 64, n0 = nt * 32;
    __shared__ float tile[64][33];
    int t = threadIdx.x;
    int col = t & 31, r8 = (t >> 5) * 8;
    #pragma unroll
    for (int i = 0; i < 8; ++i)
        tile[r8 + i][col] = src[(size_t)(k0 + r8 + i) * N + n0 + col];
    __syncthreads();
    int ksl = t >> 6, lane = t & 63, l31 = lane & 31, hi = lane >> 5;
    bf16x8 v;
    #pragma unroll
    for (int j = 0; j < 8; ++j) v[j] = (__bf16)tile[ksl * 16 + hi * 8 + j][l31];
    *(bf16x8*)(dst + ((size_t)(nt * (K / 16) + (k0 >> 4) + ksl) * 64 + lane) * 8) = v;
}

// ---------------- scatter rows into fixed per-branch regions ----------------
__global__ void scatter_kernel(const int* __restrict__ cmd, int* __restrict__ cnt,
                               int* __restrict__ rowlist)
{
    int i = blockIdx.x * 256 + threadIdx.x;   // 128 x 256 = 32768 exactly
    int lane = threadIdx.x & 63;
    int cv = cmd[i];
    #pragma unroll
    for (int c = 0; c < Cc; ++c) {
        unsigned long long m = __ballot(cv == c);
        if (!m) continue;
        int leader = __ffsll(m) - 1;
        int basep = 0;
        if (lane == leader) basep = atomicAdd(&cnt[c], (int)__popcll(m));
        basep = __shfl(basep, leader);
        if (cv == c) {
            int rank = (int)__popcll(m & ((1ull << lane) - 1ull));
            rowlist[c * B_N + basep + rank] = i;
        }
    }
}

// ---------------- main fused kernel: 64 rows/block, 8 waves ----------------
// wave w owns cols w*32..+31 of H=256, computes BOTH 32-row m-tiles (B-frag reuse x2).
// LDS map: [0,32K) x-chunk dbuf (2x16K) / act1 / h   [32K,64K) s1,s3 | s2 ; act2
//          [64K,67K) head weights
__launch_bounds__(512, 4)
__global__ void branch_mlp_kernel(
    const float* __restrict__ rgb, const float* __restrict__ spd,
    const float* __restrict__ sW1, const float* __restrict__ sb1,
    const float* __restrict__ sb2, const float* __restrict__ sb3,
    const __bf16* __restrict__ ps2, const __bf16* __restrict__ ps3,
    const __bf16* __restrict__ p1, const __bf16* __restrict__ p2, const __bf16* __restrict__ p3,
    const float* __restrict__ b1, const float* __restrict__ b2, const float* __restrict__ b3,
    const float* __restrict__ hWb, const float* __restrict__ hbb,
    const float* __restrict__ hWs, const float* __restrict__ hbs,
    const float* __restrict__ hWt, const float* __restrict__ hbt,
    const int* __restrict__ cnt, const int* __restrict__ rowlist,
    float* __restrict__ out)
{
    __shared__ char lds[68608];
    float* wld = (float*)(lds + 65536);

    // XCD-chunked bijective swizzle (grid 520 = 8*65)
    int nwg = gridDim.x;
    int q = nwg >> 3;
    int bid = (blockIdx.x & 7) * q + (blockIdx.x >> 3);

    // bid -> (branch c, 64-row group g)
    int c = -1, g = 0, accg = 0;
    #pragma unroll
    for (int i = 0; i < Cc; ++i) {
        int gc = (cnt[i] + 63) >> 6;
        if (c < 0 && bid < accg + gc) { c = i; g = bid - accg; }
        accg += gc;
    }
    if (c < 0) return;
    int n_c = cnt[c];
    const int* rl = rowlist + c * B_N;

    int tid = threadIdx.x, wave = tid >> 6, lane = tid & 63, l31 = lane & 31, hi = lane >> 5;

    // head weights -> LDS (independent region; barrier A covers visibility)
    for (int i = tid; i < 768; i += 512) {
        const float* hw = (i < 256) ? hWb : (i < 512) ? hWs : hWt;
        wld[i] = hw[c * Hc + (i & 255)];
    }

    // staging identity: row r_st (0..63), 8 threads/row, 16 cols each
    int r_st = tid >> 3, sub = tid & 7;
    int rowidx = g * 64 + r_st;
    int rid_st = rl[rowidx < n_c ? rowidx : n_c - 1];
    const float* rr = rgb + (size_t)rid_st * D_RGBc;
    float sv = spd[rid_st];

    // prologue: issue rgb chunk0 + chunk1 loads (T14: consumed later)
    f32x4 La0 = *(const f32x4*)(rr + sub * 16);
    f32x4 La1 = *(const f32x4*)(rr + sub * 16 + 4);
    f32x4 La2 = *(const f32x4*)(rr + sub * 16 + 8);
    f32x4 La3 = *(const f32x4*)(rr + sub * 16 + 12);
    f32x4 Lb0 = *(const f32x4*)(rr + 128 + sub * 16);
    f32x4 Lb1 = *(const f32x4*)(rr + 128 + sub * 16 + 4);
    f32x4 Lb2 = *(const f32x4*)(rr + 128 + sub * 16 + 8);
    f32x4 Lb3 = *(const f32x4*)(rr + 128 + sub * 16 + 12);

    // s1 = tanh(spd*sW1+sb1) -> R2 [32K,48K)
    {
        int j0 = sub * 16;
        #pragma unroll
        for (int jj = 0; jj < 16; ++jj) {
            int j = j0 + jj;
            *(__bf16*)(lds + 32768 + (r_st << 8) + sw16(r_st, (j << 1))) = (__bf16)tanhf_(sv * sW1[j] + sb1[j]);
        }
    }
    // write x-chunk0 (consumes La)
    {
        bf16x8 o;
        #pragma unroll
        for (int j = 0; j < 4; ++j) { o[j] = (__bf16)La0[j]; o[4 + j] = (__bf16)La1[j]; }
        *(bf16x8*)(lds + (r_st << 8) + sw16(r_st, (sub * 16) << 1)) = o;
        #pragma unroll
        for (int j = 0; j < 4; ++j) { o[j] = (__bf16)La2[j]; o[4 + j] = (__bf16)La3[j]; }
        *(bf16x8*)(lds + (r_st << 8) + sw16(r_st, (sub * 16 + 8) << 1)) = o;
    }
    __syncthreads();                                                   // A

    int mt = wave >> 2, nt = wave & 3;                                 // speed decomposition
    int srowA = mt * 32 + l31;

    // s2 = tanh(s1 @ sW2) -> R3 [48K,64K)
    f32x16 sacc;
    #pragma unroll
    for (int j = 0; j < 16; ++j) sacc[j] = 0.f;
    {
        const __bf16* pw = ps2 + ((size_t)(nt * 8) * 64 + lane) * 8;
        #pragma unroll
        for (int ks = 0; ks < 8; ++ks) {
            bf16x8 a = *(const bf16x8*)(lds + 32768 + (srowA << 8) + sw16(srowA, (ks * 16 + hi * 8) << 1));
            bf16x8 b = *(const bf16x8*)(pw + (size_t)ks * 512);
            sacc = __builtin_amdgcn_mfma_f32_32x32x16_bf16(a, b, sacc, 0, 0, 0);
        }
    }
    {
        int col = nt * 32 + l31;
        float bv = sb2[col];
        #pragma unroll
        for (int rg = 0; rg < 16; ++rg) {
            int row = mt * 32 + (rg & 3) + 8 * (rg >> 2) + 4 * hi;
            *(__bf16*)(lds + 49152 + (row << 8) + sw16(row, col << 1)) = (__bf16)tanhf_(sacc[rg] + bv);
        }
    }
    // reload La <- chunk2
    La0 = *(const f32x4*)(rr + 256 + sub * 16);
    La1 = *(const f32x4*)(rr + 256 + sub * 16 + 4);
    La2 = *(const f32x4*)(rr + 256 + sub * 16 + 8);
    La3 = *(const f32x4*)(rr + 256 + sub * 16 + 12);
    __syncthreads();                                                   // B

    // s3 = tanh(s2 @ sW3) -> R2 (s1 dead)
    #pragma unroll
    for (int j = 0; j < 16; ++j) sacc[j] = 0.f;
    {
        const __bf16* pw = ps3 + ((size_t)(nt * 8) * 64 + lane) * 8;
        #pragma unroll
        for (int ks = 0; ks < 8; ++ks) {
            bf16x8 a = *(const bf16x8*)(lds + 49152 + (srowA << 8) + sw16(srowA, (ks * 16 + hi * 8) << 1));
            bf16x8 b = *(const bf16x8*)(pw + (size_t)ks * 512);
            sacc = __builtin_amdgcn_mfma_f32_32x32x16_bf16(a, b, sacc, 0, 0, 0);
        }
    }
    {
        int col = nt * 32 + l31;
        float bv = sb3[col];
        #pragma unroll
        for (int rg = 0; rg < 16; ++rg) {
            int row = mt * 32 + (rg & 3) + 8 * (rg >> 2) + 4 * hi;
            *(__bf16*)(lds + 32768 + (row << 8) + sw16(row, col << 1)) = (__bf16)tanhf_(sacc[rg] + bv);
        }
    }
    // write x-chunk1 (consumes Lb); reload Lb <- chunk3
    {
        bf16x8 o;
        #pragma unroll
        for (int j = 0; j < 4; ++j) { o[j] = (__bf16)Lb0[j]; o[4 + j] = (__bf16)Lb1[j]; }
        *(bf16x8*)(lds + 16384 + (r_st << 8) + sw16(r_st, (sub * 16) << 1)) = o;
        #pragma unroll
        for (int j = 0; j < 4; ++j) { o[j] = (__bf16)Lb2[j]; o[4 + j] = (__bf16)Lb3[j]; }
        *(bf16x8*)(lds + 16384 + (r_st << 8) + sw16(r_st, (sub * 16 + 8) << 1)) = o;
    }
    Lb0 = *(const f32x4*)(rr + 384 + sub * 16);
    Lb1 = *(const f32x4*)(rr + 384 + sub * 16 + 4);
    Lb2 = *(const f32x4*)(rr + 384 + sub * 16 + 8);
    Lb3 = *(const f32x4*)(rr + 384 + sub * 16 + 12);
    __syncthreads();                                                   // C

    // ---------------- layer 1: K=640 (4 rgb chunks + s3), N-tile = wave ----------------
    f32x16 acc0, acc1;
    #pragma unroll
    for (int j = 0; j < 16; ++j) { acc0[j] = 0.f; acc1[j] = 0.f; }
    int rowA0 = l31, rowA1 = 32 + l31;
    const __bf16* p1w = p1 + (size_t)c * Hc * D_INc + ((size_t)(wave * 40) * 64 + lane) * 8;

    #define L1_CHUNK(BUFB, KF0)                                                              \
    {                                                                                        \
        _Pragma("unroll")                                                                    \
        for (int ks = 0; ks < 8; ++ks) {                                                     \
            bf16x8 a0 = *(const bf16x8*)(lds + (BUFB) + (rowA0 << 8) + sw16(rowA0, (ks * 16 + hi * 8) << 1)); \
            bf16x8 a1 = *(const bf16x8*)(lds + (BUFB) + (rowA1 << 8) + sw16(rowA1, (ks * 16 + hi * 8) << 1)); \
            bf16x8 b = *(const bf16x8*)(p1w + (size_t)((KF0) + ks) * 512);                   \
            acc0 = __builtin_amdgcn_mfma_f32_32x32x16_bf16(a0, b, acc0, 0, 0, 0);            \
            acc1 = __builtin_amdgcn_mfma_f32_32x32x16_bf16(a1, b, acc1, 0, 0, 0);            \
        }                                                                                    \
    }

    L1_CHUNK(0, 0)                                 // chunk0 from buf0
    __syncthreads();                               // D1
    L1_CHUNK(16384, 8)                             // chunk1 from buf1
    {   // write chunk2 -> buf0 (consumes La)
        bf16x8 o;
        #pragma unroll
        for (int j = 0; j < 4; ++j) { o[j] = (__bf16)La0[j]; o[4 + j] = (__bf16)La1[j]; }
        *(bf16x8*)(lds + (r_st << 8) + sw16(r_st, (sub * 16) << 1)) = o;
        #pragma unroll
        for (int j = 0; j < 4; ++j) { o[j] = (__bf16)La2[j]; o[4 + j] = (__bf16)La3[j]; }
        *(bf16x8*)(lds + (r_st << 8) + sw16(r_st, (sub * 16 + 8) << 1)) = o;
    }
    __syncthreads();                               // D2
    L1_CHUNK(0, 16)                                // chunk2 from buf0
    {   // write chunk3 -> buf1 (consumes Lb)
        bf16x8 o;
        #pragma unroll
        for (int j = 0; j < 4; ++j) { o[j] = (__bf16)Lb0[j]; o[4 + j] = (__bf16)Lb1[j]; }
        *(bf16x8*)(lds + 16384 + (r_st << 8) + sw16(r_st, (sub * 16) << 1)) = o;
        #pragma unroll
        for (int j = 0; j < 4; ++j) { o[j] = (__bf16)Lb2[j]; o[4 + j] = (__bf16)Lb3[j]; }
        *(bf16x8*)(lds + 16384 + (r_st << 8) + sw16(r_st, (sub * 16 + 8) << 1)) = o;
    }
    __syncthreads();                               // D3
    L1_CHUNK(16384, 24)                            // chunk3 from buf1
    {   // s3 part: K 512..639 from R2
        #pragma unroll
        for (int ks = 0; ks < 8; ++ks) {
            bf16x8 a0 = *(const bf16x8*)(lds + 32768 + (rowA0 << 8) + sw16(rowA0, (ks * 16 + hi * 8) << 1));
            bf16x8 a1 = *(const bf16x8*)(lds + 32768 + (rowA1 << 8) + sw16(rowA1, (ks * 16 + hi * 8) << 1));
            bf16x8 b = *(const bf16x8*)(p1w + (size_t)(32 + ks) * 512);
            acc0 = __builtin_amdgcn_mfma_f32_32x32x16_bf16(a0, b, acc0, 0, 0, 0);
            acc1 = __builtin_amdgcn_mfma_f32_32x32x16_bf16(a1, b, acc1, 0, 0, 0);
        }
    }
    __syncthreads();                               // E (all x-buf reads done)

    // act1 = sigmoid(.+b1) -> R1 [0,32K): chunked aoff
    int colW = wave * 32 + l31;
    {
        float bv = b1[c * Hc + colW];
        int cb = (colW >> 7) << 14, cl = (colW & 127) << 1;
        #pragma unroll
        for (int rg = 0; rg < 16; ++rg) {
            int row0 = (rg & 3) + 8 * (rg >> 2) + 4 * hi;
            *(__bf16*)(lds + cb + (row0 << 8) + sw16(row0, cl)) = (__bf16)sigmoidf_(acc0[rg] + bv);
            int row1 = 32 + row0;
            *(__bf16*)(lds + cb + (row1 << 8) + sw16(row1, cl)) = (__bf16)sigmoidf_(acc1[rg] + bv);
        }
    }
    __syncthreads();                               // F

    // ---------------- layer 2: K=256, A from R1, act2 -> [32K,64K) ----------------
    #pragma unroll
    for (int j = 0; j < 16; ++j) { acc0[j] = 0.f; acc1[j] = 0.f; }
    {
        const __bf16* p2w = p2 + (size_t)c * Hc * Hc + ((size_t)(wave * 16) * 64 + lane) * 8;
        #pragma unroll
        for (int ks = 0; ks < 16; ++ks) {
            int kcol = ks * 16 + hi * 8;
            int cb = (kcol >> 7) << 14, cl = (kcol & 127) << 1;
            bf16x8 a0 = *(const bf16x8*)(lds + cb + (rowA0 << 8) + sw16(rowA0, cl));
            bf16x8 a1 = *(const bf16x8*)(lds + cb + (rowA1 << 8) + sw16(rowA1, cl));
            bf16x8 b = *(const bf16x8*)(p2w + (size_t)ks * 512);
            acc0 = __builtin_amdgcn_mfma_f32_32x32x16_bf16(a0, b, acc0, 0, 0, 0);
            acc1 = __builtin_amdgcn_mfma_f32_32x32x16_bf16(a1, b, acc1, 0, 0, 0);
        }
    }
    {
        float bv = b2[c * Hc + colW];
        int cb = 32768 + ((colW >> 7) << 14), cl = (colW & 127) << 1;
        #pragma unroll
        for (int rg = 0; rg < 16; ++rg) {
            int row0 = (rg & 3) + 8 * (rg >> 2) + 4 * hi;
            *(__bf16*)(lds + cb + (row0 << 8) + sw16(row0, cl)) = (__bf16)sigmoidf_(acc0[rg] + bv);
            int row1 = 32 + row0;
            *(__bf16*)(lds + cb + (row1 << 8) + sw16(row1, cl)) = (__bf16)sigmoidf_(acc1[rg] + bv);
        }
    }
    __syncthreads();                               // G

    // ---------------- layer 3: K=256, A from [32K,64K), h -> R1 ----------------
    #pragma unroll
    for (int j = 0; j < 16; ++j) { acc0[j] = 0.f; acc1[j] = 0.f; }
    {
        const __bf16* p3w = p3 + (size_t)c * Hc * Hc + ((size_t)(wave * 16) * 64 + lane) * 8;
        #pragma unroll
        for (int ks = 0; ks < 16; ++ks) {
            int kcol = ks * 16 + hi * 8;
            int cb = 32768 + ((kcol >> 7) << 14), cl = (kcol & 127) << 1;
            bf16x8 a0 = *(const bf16x8*)(lds + cb + (rowA0 << 8) + sw16(rowA0, cl));
            bf16x8 a1 = *(const bf16x8*)(lds + cb + (rowA1 << 8) + sw16(rowA1, cl));
            bf16x8 b = *(const bf16x8*)(p3w + (size_t)ks * 512);
            acc0 = __builtin_amdgcn_mfma_f32_32x32x16_bf16(a0, b, acc0, 0, 0, 0);
            acc1 = __builtin_amdgcn_mfma_f32_32x32x16_bf16(a1, b, acc1, 0, 0, 0);
        }
    }
    {
        float bv = b3[c * Hc + colW];
        int cb = (colW >> 7) << 14, cl = (colW & 127) << 1;
        #pragma unroll
        for (int rg = 0; rg < 16; ++rg) {
            int row0 = (rg & 3) + 8 * (rg >> 2) + 4 * hi;
            *(__bf16*)(lds + cb + (row0 << 8) + sw16(row0, cl)) = (__bf16)sigmoidf_(acc0[rg] + bv);
            int row1 = 32 + row0;
            *(__bf16*)(lds + cb + (row1 << 8) + sw16(row1, cl)) = (__bf16)sigmoidf_(acc1[rg] + bv);
        }
    }
    __syncthreads();                               // H

    // ---------------- heads: per row dot(h, w) over 256 cols ----------------
    {
        int row = r_st, t8 = sub;                  // 8 threads per row, 32 cols each
        float pr0 = 0.f, pr1 = 0.f, pr2 = 0.f;
        #pragma unroll
        for (int q2 = 0; q2 < 4; ++q2) {
            int col0 = t8 * 32 + q2 * 8;
            int cb = (col0 >> 7) << 14, cl = (col0 & 127) << 1;
            bf16x8 hv = *(const bf16x8*)(lds + cb + (row << 8) + sw16(row, cl));
            #pragma unroll
            for (int e = 0; e < 8; ++e) {
                float h = (float)hv[e];
                int col = col0 + e;
                pr0 += h * wld[col];
                pr1 += h * wld[256 + col];
                pr2 += h * wld[512 + col];
            }
        }
        #pragma unroll
        for (int m = 1; m < 8; m <<= 1) {
            pr0 += __shfl_xor(pr0, m);
            pr1 += __shfl_xor(pr1, m);
            pr2 += __shfl_xor(pr2, m);
        }
        if (t8 == 0 && rowidx < n_c) {
            int R = rid_st;
            out[R]           = sigmoidf_(pr0 + hbb[c]);
            out[B_N + R]     = tanhf_(pr1 + hbs[c]);
            out[2 * B_N + R] = sigmoidf_(pr2 + hbt[c]);
        }
    }
}

extern "C" void kernel_launch(void* const* d_in, const int* in_sizes, int n_in,
                              void* d_out, int out_size, void* d_ws, size_t ws_size,
                              hipStream_t stream)
{
    const float* rgb = (const float*)d_in[0];
    const float* spd = (const float*)d_in[1];
    const int*   cmd = (const int*)d_in[2];
    const float* sW1 = (const float*)d_in[3];
    const float* sb1 = (const float*)d_in[4];
    const float* sW2 = (const float*)d_in[5];
    const float* sb2 = (const float*)d_in[6];
    const float* sW3 = (const float*)d_in[7];
    const float* sb3 = (const float*)d_in[8];
    const float* W1  = (const float*)d_in[9];
    const float* b1  = (const float*)d_in[10];
    const float* W2  = (const float*)d_in[11];
    const float* b2  = (const float*)d_in[12];
    const float* W3  = (const float*)d_in[13];
    const float* b3  = (const float*)d_in[14];
    const float* hWb = (const float*)d_in[15];
    const float* hbb = (const float*)d_in[16];
    const float* hWs = (const float*)d_in[17];
    const float* hbs = (const float*)d_in[18];
    const float* hWt = (const float*)d_in[19];
    const float* hbt = (const float*)d_in[20];

    char* ws = (char*)d_ws;
    size_t off = 0;
    auto take = [&](size_t bytes) { char* p = ws + off; off = (off + bytes + 255) & ~(size_t)255; return p; };
    __bf16* p1  = (__bf16*)take((size_t)Cc * Hc * D_INc * 2);
    __bf16* p2  = (__bf16*)take((size_t)Cc * Hc * Hc * 2);
    __bf16* p3  = (__bf16*)take((size_t)Cc * Hc * Hc * 2);
    __bf16* ps2 = (__bf16*)take((size_t)D_SPDc * D_SPDc * 2);
    __bf16* ps3 = (__bf16*)take((size_t)D_SPDc * D_SPDc * 2);
    int* rowlist = (int*)take((size_t)Cc * B_N * 4);
    int* cnt     = (int*)take(16 * 4);

    pack_kernel<<<1024, 256, 0, stream>>>(W1, W2, W3, sW2, sW3, p1, p2, p3, ps2, ps3, cnt);
    scatter_kernel<<<128, 256, 0, stream>>>(cmd, cnt, rowlist);
    branch_mlp_kernel<<<520, 512, 0, stream>>>(rgb, spd, sW1, sb1, sb2, sb3,
        ps2, ps3, p1, p2, p3, b1, b2, b3,
        hWb, hbb, hWs, hbs, hWt, hbt, cnt, rowlist, (float*)d_out);
}